// Round 1
// baseline (919.434 us; speedup 1.0000x reference)
//
#include <hip/hip_runtime.h>
#include <stdint.h>

using u16 = unsigned short;
typedef __bf16 bf16x8 __attribute__((ext_vector_type(8)));
typedef float f32x4 __attribute__((ext_vector_type(4)));
typedef u16 ushort8 __attribute__((ext_vector_type(8)));

__device__ __forceinline__ u16 f2bf(float f) {
    unsigned u = __builtin_bit_cast(unsigned, f);
    return (u16)((u + 0x7fffu + ((u >> 16) & 1u)) >> 16);
}

// global->LDS direct copy, 16B per lane. LDS dest is wave-uniform base + lane*16.
#define GLD16(gptr, lptr) __builtin_amdgcn_global_load_lds( \
    (const __attribute__((address_space(1))) void*)(unsigned long long)(gptr), \
    (__attribute__((address_space(3))) void*)(unsigned)(unsigned long long)(lptr), 16, 0, 0)

// ---------------- conversion kernels ----------------

__global__ void convert_bf16(const float* __restrict__ in, u16* __restrict__ out) {
    int gid = blockIdx.x * 256 + threadIdx.x;      // 8 f32 per thread
    const float4* in4 = (const float4*)in;
    float4 a = in4[2 * gid], b = in4[2 * gid + 1];
    ushort8 o;
    o[0] = f2bf(a.x); o[1] = f2bf(a.y); o[2] = f2bf(a.z); o[3] = f2bf(a.w);
    o[4] = f2bf(b.x); o[5] = f2bf(b.y); o[6] = f2bf(b.z); o[7] = f2bf(b.w);
    *(ushort8*)(out + (size_t)gid * 8) = o;
}

// out[C][R] = bf16(in[R][C])  -- 64x64 LDS tile transpose
__global__ void transpose_convert(const float* __restrict__ in, u16* __restrict__ out,
                                  int R, int C) {
    __shared__ u16 sT[64][65];
    const int c0 = blockIdx.x << 6, r0 = blockIdx.y << 6;
    const int tid = threadIdx.x;
#pragma unroll
    for (int rep = 0; rep < 16; rep++) {
        int idx = rep * 256 + tid;
        int r = idx >> 6, c = idx & 63;
        sT[c][r] = f2bf(in[(size_t)(r0 + r) * C + c0 + c]);
    }
    __syncthreads();
#pragma unroll
    for (int rep = 0; rep < 16; rep++) {
        int idx = rep * 256 + tid;
        int r = idx >> 6, c = idx & 63;
        out[(size_t)(c0 + r) * R + r0 + c] = sT[r][c];
    }
}

// maskbits[i][w] bit (j&31) = (mask[i][2j+1] != 0), j = resized col index
__global__ void mask_pack(const float* __restrict__ mask, unsigned* __restrict__ mw) {
    int gid = blockIdx.x * 256 + threadIdx.x;      // 4096*2048 threads
    int i = gid >> 11, j = gid & 2047;
    float v = mask[(size_t)i * 4096 + 2 * j + 1];
    unsigned long long b = __ballot(v != 0.0f);
    int lane = threadIdx.x & 63;
    if (lane == 0)       mw[(size_t)i * 64 + (j >> 5)] = (unsigned)b;
    else if (lane == 32) mw[(size_t)i * 64 + (j >> 5)] = (unsigned)(b >> 32);
}

// ---------------- NT GEMM: C[i][j] = sum_k A[i][k]*B[j][k] ----------------
// A [M][K] row-major bf16, B [N][K] row-major bf16. 128x128 tile, BK=32, dbuf LDS.
// grid = (N/128, M/128, batches)

template <bool OUT_BF16, bool ADD_BIAS>
__global__ __launch_bounds__(256) void gemm_nt(
    const u16* __restrict__ A, int lda, long long sA,
    const u16* __restrict__ B, int ldb, long long sB,
    void* __restrict__ Cp, int ldc, long long sC,
    const float* __restrict__ bias, int K) {
    __shared__ __align__(16) u16 lds[2][2][4][128][8];   // [buf][mat][kblk][row][8] = 32KB
    const int bz = blockIdx.z;
    const u16* Ab = A + (size_t)sA * bz;
    const u16* Bb = B + (size_t)sB * bz;
    const int m0 = blockIdx.y << 7, n0 = blockIdx.x << 7;
    const int tid = threadIdx.x, wave = tid >> 6, lane = tid & 63;
    const int kg = lane >> 4, lr = lane & 15;
    const int wr = (wave >> 1) << 6, wc = (wave & 1) << 6;
    const int nT = K >> 5;
    f32x4 acc[4][4] = {};

    // prologue: stage tile 0 into buf 0. wave stages kblk==wave, rows i*64+lane.
#pragma unroll
    for (int i = 0; i < 2; i++) {
        int row = i * 64 + lane;
        GLD16(Ab + (size_t)(m0 + row) * lda + wave * 8, &lds[0][0][wave][i * 64][0]);
        GLD16(Bb + (size_t)(n0 + row) * ldb + wave * 8, &lds[0][1][wave][i * 64][0]);
    }
    for (int t = 0; t < nT; ++t) {
        const int cur = t & 1;
        if (t + 1 < nT) {
            const int nxt = cur ^ 1;
            const int koff = (t + 1) << 5;
#pragma unroll
            for (int i = 0; i < 2; i++) {
                int row = i * 64 + lane;
                GLD16(Ab + (size_t)(m0 + row) * lda + koff + wave * 8, &lds[nxt][0][wave][i * 64][0]);
                GLD16(Bb + (size_t)(n0 + row) * ldb + koff + wave * 8, &lds[nxt][1][wave][i * 64][0]);
            }
        }
        __syncthreads();   // drains vmcnt -> buf[cur] ready
        bf16x8 af[4], bfv[4];
#pragma unroll
        for (int mi = 0; mi < 4; mi++)
            af[mi] = *(const bf16x8*)&lds[cur][0][kg][wr + mi * 16 + lr][0];
#pragma unroll
        for (int ni = 0; ni < 4; ni++)
            bfv[ni] = *(const bf16x8*)&lds[cur][1][kg][wc + ni * 16 + lr][0];
#pragma unroll
        for (int mi = 0; mi < 4; mi++)
#pragma unroll
            for (int ni = 0; ni < 4; ni++)
                acc[mi][ni] = __builtin_amdgcn_mfma_f32_16x16x32_bf16(af[mi], bfv[ni], acc[mi][ni], 0, 0, 0);
        __syncthreads();   // all reads of buf[cur] done before it is re-staged
    }

    if constexpr (OUT_BF16) {
        u16* C = (u16*)Cp + (size_t)sC * bz;
#pragma unroll
        for (int mi = 0; mi < 4; mi++)
#pragma unroll
            for (int ni = 0; ni < 4; ni++)
#pragma unroll
                for (int r = 0; r < 4; r++) {
                    int gr = m0 + wr + mi * 16 + kg * 4 + r;
                    int gc = n0 + wc + ni * 16 + lr;
                    C[(size_t)gr * ldc + gc] = f2bf(acc[mi][ni][r]);
                }
    } else {
        float* C = (float*)Cp + (size_t)sC * bz;
#pragma unroll
        for (int mi = 0; mi < 4; mi++)
#pragma unroll
            for (int ni = 0; ni < 4; ni++)
#pragma unroll
                for (int r = 0; r < 4; r++) {
                    int gr = m0 + wr + mi * 16 + kg * 4 + r;
                    int gc = n0 + wc + ni * 16 + lr;
                    float v = acc[mi][ni][r];
                    if constexpr (ADD_BIAS) v += bias[gc];
                    C[(size_t)gr * ldc + gc] = v;
                }
    }
}

// ---------------- flash attention over compressed K/V ----------------
// q  [2*4096][1024] bf16 (row = b*4096+n, head slice cols h*64..)
// kb [b][2048][1024] bf16 ; vt [b][1024][2048] bf16 (row = d, col = kp)
// mw [4096][64] packed mask bits ; ao [2*4096][1024] bf16 out
// block = 4 waves, each wave owns 16 query rows; j-tiles of 32.

__global__ __launch_bounds__(256) void attn_kernel(
    const u16* __restrict__ q, const u16* __restrict__ kb,
    const u16* __restrict__ vt, const unsigned* __restrict__ mw,
    u16* __restrict__ ao) {
    __shared__ __align__(16) u16 sP[4][4][16][8];   // [wave][kblk][row][8]
    const int tid = threadIdx.x;
    const int wave = tid >> 6, lane = tid & 63, kg = lane >> 4, lr = lane & 15;
    const int b = blockIdx.y >> 4, h = blockIdx.y & 15;
    const int nrow = (blockIdx.x << 6) + wave * 16;

    const u16* qrow = q + (size_t)(b * 4096 + nrow + lr) * 1024 + h * 64 + kg * 8;
    bf16x8 aq0 = *(const bf16x8*)qrow;
    bf16x8 aq1 = *(const bf16x8*)(qrow + 32);
    const u16* kh = kb + (size_t)b * 2048 * 1024 + h * 64;
    const u16* vh = vt + (size_t)b * 1024 * 2048 + (size_t)(h * 64) * 2048;
    const unsigned* mrow = mw + (size_t)(nrow + kg * 4) * 64;

    f32x4 o[4] = {};
    float mrun[4], lrun[4];
#pragma unroll
    for (int r = 0; r < 4; r++) { mrun[r] = -3.0e38f; lrun[r] = 0.0f; }

    for (int j0 = 0; j0 < 2048; j0 += 32) {
        f32x4 s0 = {0.f, 0.f, 0.f, 0.f}, s1 = {0.f, 0.f, 0.f, 0.f};
        {
            const u16* kr0 = kh + (size_t)(j0 + lr) * 1024 + kg * 8;
            s0 = __builtin_amdgcn_mfma_f32_16x16x32_bf16(aq0, *(const bf16x8*)kr0, s0, 0, 0, 0);
            s0 = __builtin_amdgcn_mfma_f32_16x16x32_bf16(aq1, *(const bf16x8*)(kr0 + 32), s0, 0, 0, 0);
            const u16* kr1 = kh + (size_t)(j0 + 16 + lr) * 1024 + kg * 8;
            s1 = __builtin_amdgcn_mfma_f32_16x16x32_bf16(aq0, *(const bf16x8*)kr1, s1, 0, 0, 0);
            s1 = __builtin_amdgcn_mfma_f32_16x16x32_bf16(aq1, *(const bf16x8*)(kr1 + 32), s1, 0, 0, 0);
        }
        unsigned wd[4];
#pragma unroll
        for (int r = 0; r < 4; r++) wd[r] = mrow[(size_t)r * 64 + (j0 >> 5)];
        float sv0[4], sv1[4];
#pragma unroll
        for (int r = 0; r < 4; r++) {
            sv0[r] = s0[r] * 0.125f + (((wd[r] >> lr) & 1u) ? -1.0e9f : 0.0f);
            sv1[r] = s1[r] * 0.125f + (((wd[r] >> (16 + lr)) & 1u) ? -1.0e9f : 0.0f);
        }
        float tm[4];
#pragma unroll
        for (int r = 0; r < 4; r++) tm[r] = fmaxf(sv0[r], sv1[r]);
#pragma unroll
        for (int d2 = 1; d2 < 16; d2 <<= 1) {
#pragma unroll
            for (int r = 0; r < 4; r++) tm[r] = fmaxf(tm[r], __shfl_xor(tm[r], d2));
        }
        float al[4], p0[4], p1[4], ts[4];
#pragma unroll
        for (int r = 0; r < 4; r++) {
            float mn = fmaxf(mrun[r], tm[r]);
            al[r] = __expf(mrun[r] - mn);
            mrun[r] = mn;
            p0[r] = __expf(sv0[r] - mn);
            p1[r] = __expf(sv1[r] - mn);
            ts[r] = p0[r] + p1[r];
        }
#pragma unroll
        for (int d2 = 1; d2 < 16; d2 <<= 1) {
#pragma unroll
            for (int r = 0; r < 4; r++) ts[r] += __shfl_xor(ts[r], d2);
        }
#pragma unroll
        for (int r = 0; r < 4; r++) lrun[r] = lrun[r] * al[r] + ts[r];
#pragma unroll
        for (int f = 0; f < 4; f++)
#pragma unroll
            for (int r = 0; r < 4; r++) o[f][r] *= al[r];
        // P (16 rows x 32 cols) -> LDS in [kblk][row][8] subtile form
#pragma unroll
        for (int r = 0; r < 4; r++) {
            sP[wave][lr >> 3][kg * 4 + r][lr & 7] = f2bf(p0[r]);
            sP[wave][2 + (lr >> 3)][kg * 4 + r][lr & 7] = f2bf(p1[r]);
        }
        asm volatile("s_waitcnt lgkmcnt(0)" ::: "memory");
        bf16x8 ap = *(const bf16x8*)&sP[wave][kg][lr][0];
#pragma unroll
        for (int f = 0; f < 4; f++) {
            const u16* vr = vh + (size_t)(f * 16 + lr) * 2048 + j0 + kg * 8;
            o[f] = __builtin_amdgcn_mfma_f32_16x16x32_bf16(ap, *(const bf16x8*)vr, o[f], 0, 0, 0);
        }
    }
#pragma unroll
    for (int r = 0; r < 4; r++) {
        float inv = 1.0f / lrun[r];
        size_t base = (size_t)(b * 4096 + nrow + kg * 4 + r) * 1024 + h * 64;
#pragma unroll
        for (int f = 0; f < 4; f++) ao[base + f * 16 + lr] = f2bf(o[f][r] * inv);
    }
}

// ---------------- launcher ----------------

extern "C" void kernel_launch(void* const* d_in, const int* in_sizes, int n_in,
                              void* d_out, int out_size, void* d_ws, size_t ws_size,
                              hipStream_t stream) {
    const float* x    = (const float*)d_in[0];
    const float* mask = (const float*)d_in[1];
    const float* Wq   = (const float*)d_in[2];
    const float* Wk   = (const float*)d_in[3];
    const float* Wv   = (const float*)d_in[4];
    const float* Wo   = (const float*)d_in[5];
    const float* bo   = (const float*)d_in[6];
    const float* pk   = (const float*)d_in[7];
    const float* pv   = (const float*)d_in[8];
    float* out = (float*)d_out;

    char* w = (char*)d_ws;
    auto alloc = [&](size_t bytes) { void* p = w; w += (bytes + 255) & ~(size_t)255; return p; };
    u16* xb   = (u16*)alloc((size_t)8192 * 1024 * 2);
    u16* qb   = (u16*)alloc((size_t)8192 * 1024 * 2);
    u16* xkT  = (u16*)alloc((size_t)1024 * 8192 * 2);
    u16* xvT  = (u16*)alloc((size_t)1024 * 8192 * 2);
    u16* WqT  = (u16*)alloc((size_t)1024 * 1024 * 2);
    u16* WkT  = (u16*)alloc((size_t)1024 * 1024 * 2);
    u16* WvT  = (u16*)alloc((size_t)1024 * 1024 * 2);
    u16* WoT  = (u16*)alloc((size_t)1024 * 1024 * 2);
    u16* pkT  = (u16*)alloc((size_t)2048 * 4096 * 2);
    u16* pvT  = (u16*)alloc((size_t)2048 * 4096 * 2);
    u16* kbuf = (u16*)alloc((size_t)2 * 2048 * 1024 * 2);
    u16* vtb  = (u16*)alloc((size_t)2 * 1024 * 2048 * 2);
    unsigned* mw = (unsigned*)alloc((size_t)4096 * 64 * 4);
    u16* ao = xb;   // alias: xb dead after xvT GEMM; attention writes after that

    convert_bf16<<<4096, 256, 0, stream>>>(x, xb);
    transpose_convert<<<dim3(16, 16), 256, 0, stream>>>(Wq, WqT, 1024, 1024);
    transpose_convert<<<dim3(16, 16), 256, 0, stream>>>(Wk, WkT, 1024, 1024);
    transpose_convert<<<dim3(16, 16), 256, 0, stream>>>(Wv, WvT, 1024, 1024);
    transpose_convert<<<dim3(16, 16), 256, 0, stream>>>(Wo, WoT, 1024, 1024);
    transpose_convert<<<dim3(32, 64), 256, 0, stream>>>(pk, pkT, 4096, 2048);
    transpose_convert<<<dim3(32, 64), 256, 0, stream>>>(pv, pvT, 4096, 2048);
    mask_pack<<<32768, 256, 0, stream>>>(mask, mw);

    // q = x @ Wq                  : [8192,1024] = A(xb) x B(WqT)
    gemm_nt<true, false><<<dim3(8, 64, 1), 256, 0, stream>>>(xb, 1024, 0, WqT, 1024, 0, qb, 1024, 0, nullptr, 1024);
    // xkT = (x @ Wk)^T            : [1024,8192] = A(WkT) x B(xb)
    gemm_nt<true, false><<<dim3(64, 8, 1), 256, 0, stream>>>(WkT, 1024, 0, xb, 1024, 0, xkT, 8192, 0, nullptr, 1024);
    // xvT = (x @ Wv)^T
    gemm_nt<true, false><<<dim3(64, 8, 1), 256, 0, stream>>>(WvT, 1024, 0, xb, 1024, 0, xvT, 8192, 0, nullptr, 1024);
    // k[b] = proj_k^T @ xk[b]     : [2048,1024] per b = A(pkT) x B(xkT col-slice)
    gemm_nt<true, false><<<dim3(8, 16, 2), 256, 0, stream>>>(pkT, 4096, 0, xkT, 8192, 4096, kbuf, 1024, (long long)2048 * 1024, nullptr, 4096);
    // vT[b] = xv[b]^T @ proj_v    : [1024,2048] per b = A(xvT col-slice) x B(pvT)
    gemm_nt<true, false><<<dim3(16, 8, 2), 256, 0, stream>>>(xvT, 8192, 4096, pvT, 4096, 0, vtb, 2048, (long long)1024 * 2048, nullptr, 4096);

    attn_kernel<<<dim3(64, 32), 256, 0, stream>>>(qb, kbuf, vtb, mw, ao);

    // out = ao @ Wo + bo (f32 out)
    gemm_nt<false, true><<<dim3(8, 64, 1), 256, 0, stream>>>(ao, 1024, 0, WoT, 1024, 0, out, 1024, 0, bo, 1024);
}